// Round 7
// baseline (868.040 us; speedup 1.0000x reference)
//
#include <hip/hip_runtime.h>

#define N_NODES 50000
#define N_EDGES 800000
#define N_GRAPHS 1024
#define IN_DIM 78
#define K1P 96            // IN_DIM padded to multiple of 32
#define HID 256
#define OUT_DIM 128

typedef unsigned short ushort_t;
typedef __attribute__((ext_vector_type(8))) short v8s;
typedef __attribute__((ext_vector_type(4))) float v4f;
typedef __attribute__((ext_vector_type(2))) unsigned short us2;
typedef __attribute__((ext_vector_type(4))) unsigned short us4;
typedef __attribute__((ext_vector_type(8))) unsigned short us8;

__device__ __forceinline__ ushort_t f2bf(float f) {
    unsigned u = __float_as_uint(f);
    unsigned r = (u + 0x7fffu + ((u >> 16) & 1u)) >> 16;   // RNE
    return (ushort_t)r;
}
__device__ __forceinline__ float bf2f(ushort_t h) {
    return __uint_as_float((unsigned)h << 16);
}

// ---------------- weight transpose + pad + bf16 cast: out[n][k] = W[k][n] ------
__global__ __launch_bounds__(256)
void wt_kernel(const float* __restrict__ W, ushort_t* __restrict__ out,
               int K, int N, int Kp)
{
    int i = blockIdx.x * 256 + threadIdx.x;
    if (i >= N * Kp) return;
    int n = i / Kp, k = i - n * Kp;
    float v = (k < K) ? W[(size_t)k * N + n] : 0.0f;
    out[i] = f2bf(v);
}

// ---------------- pad + cast activations: out[r][k<Kin?]=in, else 0 -----------
__global__ __launch_bounds__(256)
void pad_cast_kernel(const float* __restrict__ in, ushort_t* __restrict__ out,
                     int rows, int Kin, int Kout)
{
    int i = blockIdx.x * 256 + threadIdx.x;
    if (i >= rows * Kout) return;
    int r = i / Kout, k = i - r * Kout;
    out[i] = f2bf(k < Kin ? in[(size_t)r * Kin + k] : 0.0f);
}

// ---------------- CSR build ----------------------------------------------------
__global__ __launch_bounds__(256)
void hist_kernel(const int* __restrict__ dstI, int* __restrict__ deg, int nE)
{
    int e = blockIdx.x * 256 + threadIdx.x;
    if (e < nE) {
        int d = dstI[e];
        if ((unsigned)d < (unsigned)N_NODES) atomicAdd(&deg[d], 1);
    }
}

// hierarchical exclusive scan of deg -> rowptr (n+1 entries)
__global__ __launch_bounds__(1024)
void scan1_kernel(const int* __restrict__ deg, int* __restrict__ rowptr,
                  int* __restrict__ blocksum, int n)
{
    __shared__ int s[1024];
    int b = (int)blockIdx.x, t = (int)threadIdx.x;
    int i = b * 1024 + t;
    int v = (i < n) ? deg[i] : 0;
    s[t] = v;
    __syncthreads();
    for (int off = 1; off < 1024; off <<= 1) {
        int a = (t >= off) ? s[t - off] : 0;
        __syncthreads();
        s[t] += a;
        __syncthreads();
    }
    if (i < n) rowptr[i + 1] = s[t];      // block-local inclusive
    if (t == 1023) blocksum[b] = s[1023];
    if (b == 0 && t == 0) rowptr[0] = 0;
}

__global__ __launch_bounds__(64)
void scan2_kernel(int* __restrict__ blocksum, int nb)   // nb <= 64
{
    int t = (int)threadIdx.x;
    int v = (t < nb) ? blocksum[t] : 0;
    #pragma unroll
    for (int off = 1; off < 64; off <<= 1) {
        int a = __shfl_up(v, off, 64);
        if (t >= off) v += a;
    }
    if (t < nb) blocksum[t] = v;
}

__global__ __launch_bounds__(256)
void scan3_kernel(const int* __restrict__ blocksum, int* __restrict__ rowptr,
                  int* __restrict__ cursor, int n)
{
    int j = blockIdx.x * 256 + threadIdx.x;   // 0..n
    if (j > n) return;
    int v;
    if (j == 0) v = 0;
    else {
        int b = (j - 1) >> 10;
        v = rowptr[j] + (b >= 1 ? blocksum[b - 1] : 0);
    }
    rowptr[j] = v;
    if (j < n) cursor[j] = v;
}

__global__ __launch_bounds__(256)
void fill_kernel(const int* __restrict__ srcI, const int* __restrict__ dstI,
                 int* __restrict__ cursor, int* __restrict__ csr_src, int nE)
{
    int e = blockIdx.x * 256 + threadIdx.x;
    if (e < nE) {
        int d = dstI[e];
        int s = srcI[e];
        if ((unsigned)d < (unsigned)N_NODES && (unsigned)s < (unsigned)N_NODES) {
            int pos = atomicAdd(&cursor[d], 1);
            csr_src[pos] = s;
        }
    }
}

// ---------------- CSR aggregation, wave-per-node, vectorized gathers -----------
template<int VPT> struct VecT;
template<> struct VecT<2> { using T = us2; };
template<> struct VecT<4> { using T = us4; };
template<> struct VecT<8> { using T = us8; };

template<int VPT>
__global__ __launch_bounds__(256)
void csr_agg_wave_kernel(const ushort_t* __restrict__ feat,
                         const int* __restrict__ rowptr,
                         const int* __restrict__ csr_src,
                         ushort_t* __restrict__ out, int Ds)
{
    using T = typename VecT<VPT>::T;
    const int wv   = (int)threadIdx.x >> 6;
    const int node = (int)blockIdx.x * 4 + wv;
    if (node >= N_NODES) return;
    const int lane = (int)threadIdx.x & 63;
    const int off0 = lane * VPT;
    const bool act = off0 < Ds;                    // Ds=96: lanes 48..63 idle
    const int off  = act ? off0 : (Ds - VPT);      // clamp: redundant but safe

    const int e0 = rowptr[node], e1 = rowptr[node + 1];
    float acc[VPT];
    #pragma unroll
    for (int i = 0; i < VPT; ++i) acc[i] = 0.0f;

    int e = e0;
    for (; e + 4 <= e1; e += 4) {
        int s0 = csr_src[e + 0];
        int s1 = csr_src[e + 1];
        int s2 = csr_src[e + 2];
        int s3 = csr_src[e + 3];
        T r0 = *(const T*)(feat + (size_t)s0 * Ds + off);
        T r1 = *(const T*)(feat + (size_t)s1 * Ds + off);
        T r2 = *(const T*)(feat + (size_t)s2 * Ds + off);
        T r3 = *(const T*)(feat + (size_t)s3 * Ds + off);
        #pragma unroll
        for (int i = 0; i < VPT; ++i)
            acc[i] += (bf2f(r0[i]) + bf2f(r1[i])) + (bf2f(r2[i]) + bf2f(r3[i]));
    }
    for (; e < e1; ++e) {
        int s = csr_src[e];
        T r = *(const T*)(feat + (size_t)s * Ds + off);
        #pragma unroll
        for (int i = 0; i < VPT; ++i) acc[i] += bf2f(r[i]);
    }

    if (act) {
        T o;
        #pragma unroll
        for (int i = 0; i < VPT; ++i) o[i] = f2bf(acc[i]);
        *(T*)(out + (size_t)node * Ds + off0) = o;
    }
}

// ---------------- bf16 MFMA GEMM, barrier-free direct-to-register ---------------
// out = act( A1@W1t^T + A2@W2t^T + bias ),  A*: bf16 [M][K], W*t: bf16 [Fo][K]
// NO LDS, NO __syncthreads: each wave loads its MFMA fragments directly from
// global (16B/lane in exact A-operand layout) and feeds MFMA. Waves slide
// independently; compiler pipelines loads across k-steps with vmcnt(N)
// (AITER flatmm style). Sibling waves' duplicate A reads hit L1; cross-block
// re-reads hit L2/L3.
// Tile: 128 rows x (NT*32) cols; 4 waves in 2x2; wave = 64 x NT*16.
template<int NT>
__global__ __launch_bounds__(256, 3)
void mfma_gemm_direct(const ushort_t* __restrict__ A1,
                      const ushort_t* __restrict__ A2,
                      const ushort_t* __restrict__ W1t,
                      const ushort_t* __restrict__ W2t,
                      const float* __restrict__ bias,
                      void* __restrict__ outp,
                      int M, int K, int Fo, int relu, int out_bf16)
{
    const int tid = (int)threadIdx.x;
    const int l   = tid & 63;
    const int w   = tid >> 6;
    const int q   = l >> 4;
    const int r15 = l & 15;
    const int bm  = blockIdx.y * 128;
    const int bn  = blockIdx.x * (NT * 32);
    const int wm  = w >> 1, wn = w & 1;

    v4f acc[4][NT];
    #pragma unroll
    for (int mt = 0; mt < 4; ++mt)
        #pragma unroll
        for (int nt = 0; nt < NT; ++nt)
            acc[mt][nt] = (v4f){0.0f, 0.0f, 0.0f, 0.0f};

    // per-lane row/col indices (rows clamped: garbage rows never stored)
    int arow[4], bcol[NT];
    #pragma unroll
    for (int mt = 0; mt < 4; ++mt) {
        int row = bm + wm * 64 + mt * 16 + r15;
        arow[mt] = (row < M) ? row : (M - 1);
    }
    #pragma unroll
    for (int nt = 0; nt < NT; ++nt)
        bcol[nt] = bn + wn * (NT * 16) + nt * 16 + r15;

    const int nks = K >> 5;
    for (int pass = 0; pass < 2; ++pass) {
        const ushort_t* A  = pass ? A2  : A1;
        const ushort_t* Bt = pass ? W2t : W1t;
        if (A == nullptr) break;
        const ushort_t* ap[4];
        const ushort_t* bp[NT];
        #pragma unroll
        for (int mt = 0; mt < 4; ++mt)
            ap[mt] = A + (size_t)arow[mt] * K + q * 8;
        #pragma unroll
        for (int nt = 0; nt < NT; ++nt)
            bp[nt] = Bt + (size_t)bcol[nt] * K + q * 8;

        #pragma unroll 4
        for (int ks = 0; ks < nks; ++ks) {
            v8s af[4], bf[NT];
            #pragma unroll
            for (int mt = 0; mt < 4; ++mt)
                af[mt] = *(const v8s*)(ap[mt] + ks * 32);
            #pragma unroll
            for (int nt = 0; nt < NT; ++nt)
                bf[nt] = *(const v8s*)(bp[nt] + ks * 32);
            #pragma unroll
            for (int mt = 0; mt < 4; ++mt)
                #pragma unroll
                for (int nt = 0; nt < NT; ++nt)
                    acc[mt][nt] = __builtin_amdgcn_mfma_f32_16x16x32_bf16(
                        af[mt], bf[nt], acc[mt][nt], 0, 0, 0);
        }
    }

    // epilogue: C/D map col=lane&15, row=q*4+reg
    #pragma unroll
    for (int nt = 0; nt < NT; ++nt) {
        int col = bcol[nt];
        float bb = bias[col];
        #pragma unroll
        for (int mt = 0; mt < 4; ++mt) {
            #pragma unroll
            for (int p = 0; p < 4; ++p) {
                int row = bm + wm * 64 + mt * 16 + q * 4 + p;
                if (row < M) {
                    float v = acc[mt][nt][p] + bb;
                    if (relu) v = fmaxf(v, 0.0f);
                    if (out_bf16) ((ushort_t*)outp)[(size_t)row * Fo + col] = f2bf(v);
                    else          ((float*)outp)[(size_t)row * Fo + col]   = v;
                }
            }
        }
    }
}

// ---------------- LayerNorm(128) + ReLU + x_atom + atomic pool -----------------
__global__ __launch_bounds__(128)
void ln_relu_pool_kernel(const float* __restrict__ z,
                         const float* __restrict__ gamma,
                         const float* __restrict__ beta,
                         const int* __restrict__ batch,
                         float* __restrict__ x_atom,
                         float* __restrict__ pooled)
{
    int row = (int)blockIdx.x;
    int t = (int)threadIdx.x;     // 0..127
    float v = z[(long long)row * 128 + t];

    __shared__ float red[2];
    float s = v;
    #pragma unroll
    for (int o = 32; o >= 1; o >>= 1) s += __shfl_xor(s, o, 64);
    int wave = t >> 6;
    if ((t & 63) == 0) red[wave] = s;
    __syncthreads();
    float mean = (red[0] + red[1]) * (1.0f / 128.0f);

    float d = v - mean;
    float s2 = d * d;
    #pragma unroll
    for (int o = 32; o >= 1; o >>= 1) s2 += __shfl_xor(s2, o, 64);
    __syncthreads();
    if ((t & 63) == 0) red[wave] = s2;
    __syncthreads();
    float var = (red[0] + red[1]) * (1.0f / 128.0f);

    float y = d * rsqrtf(var + 1e-5f) * gamma[t] + beta[t];
    y = fmaxf(y, 0.0f);
    x_atom[(long long)row * 128 + t] = y;
    int b = batch[row];
    if ((unsigned)b < (unsigned)N_GRAPHS)
        atomicAdd(pooled + (long long)b * 128 + t, y);
}

extern "C" void kernel_launch(void* const* d_in, const int* in_sizes, int n_in,
                              void* d_out, int out_size, void* d_ws, size_t ws_size,
                              hipStream_t stream)
{
    const float* x     = (const float*)d_in[0];
    const int*   ei    = (const int*)d_in[1];
    const int*   batch = (const int*)d_in[2];
    const float* W1r   = (const float*)d_in[3];
    const float* b1    = (const float*)d_in[4];
    const float* W1o   = (const float*)d_in[5];
    const float* W2r   = (const float*)d_in[6];
    const float* b2    = (const float*)d_in[7];
    const float* W2o   = (const float*)d_in[8];
    const float* W3r   = (const float*)d_in[9];
    const float* b3    = (const float*)d_in[10];
    const float* W3o   = (const float*)d_in[11];
    const float* Wfc   = (const float*)d_in[12];
    const float* bfc   = (const float*)d_in[13];
    const float* lng   = (const float*)d_in[14];
    const float* lnb   = (const float*)d_in[15];

    const size_t WS_NEED = 204800000;
    if (ws_size < WS_NEED) {
        hipMemsetAsync(d_out, 0, (size_t)out_size * sizeof(float), stream);
        return;
    }

    char* ws = (char*)d_ws;
    // layout (bytes)
    ushort_t* xb   = (ushort_t*)(ws + 0);            // 50000x96 bf16   = 9.6e6
    ushort_t* h1   = (ushort_t*)(ws + 9600000);      // 50000x256 bf16  = 25.6e6
    float*    z    = (float*)   (ws + 0);            // 50000x128 f32 (xb/h1 dead)
    ushort_t* aggr = (ushort_t*)(ws + 35200000);     // up to 50000x512 bf16
    ushort_t* h2   = (ushort_t*)(ws + 86400000);     // 50000x512 bf16
    ushort_t* h3   = (ushort_t*)(ws + 137600000);    // 50000x512 bf16
    int* deg    = (int*)(ws + 188800000);            // 50000
    int* rowptr = (int*)(ws + 189000000);            // 50001
    int* cursor = (int*)(ws + 189200128);            // 50000
    int* csrsrc = (int*)(ws + 189400128);            // 800000
    int* blksum = (int*)(ws + 192600128);            // 64
    ushort_t* wt = (ushort_t*)(ws + 192600512);
    ushort_t* w1r_t = wt;                 // 256x96
    ushort_t* w1o_t = w1r_t + 24576;      // 256x96
    ushort_t* w2r_t = w1o_t + 24576;      // 512x256
    ushort_t* w2o_t = w2r_t + 131072;     // 512x256
    ushort_t* w3r_t = w2o_t + 131072;     // 512x512
    ushort_t* w3o_t = w3r_t + 262144;     // 512x512
    ushort_t* wfc_t = w3o_t + 262144;     // 128x512

    float* x_atom = (float*)d_out;
    float* pooled = x_atom + (size_t)N_NODES * OUT_DIM;

    const int* src = ei;
    const int* dst = ei + N_EDGES;

    // ---- conversions: weights (transpose+pad+bf16), x (pad+bf16) ----
    wt_kernel<<<(256 * K1P + 255) / 256, 256, 0, stream>>>(W1r, w1r_t, IN_DIM, HID, K1P);
    wt_kernel<<<(256 * K1P + 255) / 256, 256, 0, stream>>>(W1o, w1o_t, IN_DIM, HID, K1P);
    wt_kernel<<<(512 * 256 + 255) / 256, 256, 0, stream>>>(W2r, w2r_t, HID, 2 * HID, HID);
    wt_kernel<<<(512 * 256 + 255) / 256, 256, 0, stream>>>(W2o, w2o_t, HID, 2 * HID, HID);
    wt_kernel<<<(512 * 512 + 255) / 256, 256, 0, stream>>>(W3r, w3r_t, 2 * HID, 2 * HID, 2 * HID);
    wt_kernel<<<(512 * 512 + 255) / 256, 256, 0, stream>>>(W3o, w3o_t, 2 * HID, 2 * HID, 2 * HID);
    wt_kernel<<<(128 * 512 + 255) / 256, 256, 0, stream>>>(Wfc, wfc_t, 2 * HID, OUT_DIM, 2 * HID);
    pad_cast_kernel<<<((N_NODES * K1P) + 255) / 256, 256, 0, stream>>>(x, xb, N_NODES, IN_DIM, K1P);

    // ---- CSR build ----
    hipMemsetAsync(deg, 0, N_NODES * sizeof(int), stream);
    hist_kernel<<<(N_EDGES + 255) / 256, 256, 0, stream>>>(dst, deg, N_EDGES);
    {
        int nb = (N_NODES + 1023) / 1024;   // 49
        scan1_kernel<<<nb, 1024, 0, stream>>>(deg, rowptr, blksum, N_NODES);
        scan2_kernel<<<1, 64, 0, stream>>>(blksum, nb);
        scan3_kernel<<<(N_NODES + 1 + 255) / 256, 256, 0, stream>>>(blksum, rowptr, cursor, N_NODES);
    }
    fill_kernel<<<(N_EDGES + 255) / 256, 256, 0, stream>>>(src, dst, cursor, csrsrc, N_EDGES);

    const int GY = (N_NODES + 127) / 128;
    const int AGG_BLKS = (N_NODES + 3) / 4;

    // ---- layer 1: 78(pad96) -> 256 ----
    csr_agg_wave_kernel<2><<<AGG_BLKS, 256, 0, stream>>>(xb, rowptr, csrsrc, aggr, K1P);
    {
        dim3 g(HID / 128, GY);
        mfma_gemm_direct<4><<<g, 256, 0, stream>>>(aggr, xb, w1r_t, w1o_t, b1, h1,
                                                   N_NODES, K1P, HID, 1, 1);
    }
    // ---- layer 2: 256 -> 512 ----
    csr_agg_wave_kernel<4><<<AGG_BLKS, 256, 0, stream>>>(h1, rowptr, csrsrc, aggr, HID);
    {
        dim3 g((2 * HID) / 128, GY);
        mfma_gemm_direct<4><<<g, 256, 0, stream>>>(aggr, h1, w2r_t, w2o_t, b2, h2,
                                                   N_NODES, HID, 2 * HID, 1, 1);
    }
    // ---- layer 3: 512 -> 512 ----
    csr_agg_wave_kernel<8><<<AGG_BLKS, 256, 0, stream>>>(h2, rowptr, csrsrc, aggr, 2 * HID);
    {
        dim3 g((2 * HID) / 128, GY);
        mfma_gemm_direct<4><<<g, 256, 0, stream>>>(aggr, h2, w3r_t, w3o_t, b3, h3,
                                                   N_NODES, 2 * HID, 2 * HID, 1, 1);
    }
    // ---- fc: 512 -> 128, fp32 out, no relu ----
    {
        dim3 g(OUT_DIM / 128, GY);
        mfma_gemm_direct<4><<<g, 256, 0, stream>>>(h3, nullptr, wfc_t, nullptr, bfc, z,
                                                   N_NODES, 2 * HID, OUT_DIM, 0, 0);
    }
    // ---- LN + ReLU + pool ----
    hipMemsetAsync(pooled, 0, (size_t)N_GRAPHS * OUT_DIM * sizeof(float), stream);
    ln_relu_pool_kernel<<<N_NODES, 128, 0, stream>>>(z, lng, lnb, batch, x_atom, pooled);
}

// Round 8
// 692.668 us; speedup vs baseline: 1.2532x; 1.2532x over previous
//
#include <hip/hip_runtime.h>

#define N_NODES 50000
#define N_EDGES 800000
#define N_GRAPHS 1024
#define IN_DIM 78
#define K1P 96            // IN_DIM padded to multiple of 32
#define HID 256
#define OUT_DIM 128

typedef unsigned short ushort_t;
typedef __attribute__((ext_vector_type(8))) short v8s;
typedef __attribute__((ext_vector_type(4))) float v4f;
typedef __attribute__((ext_vector_type(4))) unsigned int u4;
typedef __attribute__((ext_vector_type(2))) unsigned short us2;
typedef __attribute__((ext_vector_type(4))) unsigned short us4;
typedef __attribute__((ext_vector_type(8))) unsigned short us8;

__device__ __forceinline__ ushort_t f2bf(float f) {
    unsigned u = __float_as_uint(f);
    unsigned r = (u + 0x7fffu + ((u >> 16) & 1u)) >> 16;   // RNE
    return (ushort_t)r;
}
__device__ __forceinline__ float bf2f(ushort_t h) {
    return __uint_as_float((unsigned)h << 16);
}

// ------------- fused weight transpose+pad+bf16 for ALL weights (1 launch) ------
// segments (elements of transposed+padded output):
//  0: w1r_t 256x96  from W1r(78x256)    off 0
//  1: w1o_t 256x96  from W1o            off 24576
//  2: w2r_t 512x256 from W2r(256x512)   off 49152
//  3: w2o_t 512x256 from W2o            off 180224
//  4: w3r_t 512x512 from W3r(512x512)   off 311296
//  5: w3o_t 512x512 from W3o            off 573440
//  6: wfc_t 128x512 from Wfc(512x128)   off 835584   total 901120
__global__ __launch_bounds__(256)
void wt_all_kernel(const float* __restrict__ W1r, const float* __restrict__ W1o,
                   const float* __restrict__ W2r, const float* __restrict__ W2o,
                   const float* __restrict__ W3r, const float* __restrict__ W3o,
                   const float* __restrict__ Wfc, ushort_t* __restrict__ out)
{
    int i = blockIdx.x * 256 + threadIdx.x;
    if (i >= 901120) return;
    const float* W; int K, N, Kp, base;
    if      (i < 24576)  { W = W1r; K = IN_DIM; N = HID;     Kp = 96;  base = 0; }
    else if (i < 49152)  { W = W1o; K = IN_DIM; N = HID;     Kp = 96;  base = 24576; }
    else if (i < 180224) { W = W2r; K = HID;    N = 2 * HID; Kp = 256; base = 49152; }
    else if (i < 311296) { W = W2o; K = HID;    N = 2 * HID; Kp = 256; base = 180224; }
    else if (i < 573440) { W = W3r; K = 2*HID;  N = 2 * HID; Kp = 512; base = 311296; }
    else if (i < 835584) { W = W3o; K = 2*HID;  N = 2 * HID; Kp = 512; base = 573440; }
    else                 { W = Wfc; K = 2*HID;  N = OUT_DIM; Kp = 512; base = 835584; }
    int j = i - base;
    int n = j / Kp, k = j - n * Kp;
    float v = (k < K) ? W[(size_t)k * N + n] : 0.0f;
    out[i] = f2bf(v);
}

// ---------------- pad + cast activations: out[r][k<Kin?]=in, else 0 -----------
__global__ __launch_bounds__(256)
void pad_cast_kernel(const float* __restrict__ in, ushort_t* __restrict__ out,
                     int rows, int Kin, int Kout)
{
    int i = blockIdx.x * 256 + threadIdx.x;
    if (i >= rows * Kout) return;
    int r = i / Kout, k = i - r * Kout;
    out[i] = f2bf(k < Kin ? in[(size_t)r * Kin + k] : 0.0f);
}

// ---------------- CSR build ----------------------------------------------------
__global__ __launch_bounds__(256)
void hist_kernel(const int* __restrict__ dstI, int* __restrict__ deg, int nE)
{
    int e = blockIdx.x * 256 + threadIdx.x;
    if (e < nE) {
        int d = dstI[e];
        if ((unsigned)d < (unsigned)N_NODES) atomicAdd(&deg[d], 1);
    }
}

__global__ __launch_bounds__(1024)
void scan1_kernel(const int* __restrict__ deg, int* __restrict__ rowptr,
                  int* __restrict__ blocksum, int n)
{
    __shared__ int s[1024];
    int b = (int)blockIdx.x, t = (int)threadIdx.x;
    int i = b * 1024 + t;
    int v = (i < n) ? deg[i] : 0;
    s[t] = v;
    __syncthreads();
    for (int off = 1; off < 1024; off <<= 1) {
        int a = (t >= off) ? s[t - off] : 0;
        __syncthreads();
        s[t] += a;
        __syncthreads();
    }
    if (i < n) rowptr[i + 1] = s[t];      // block-local inclusive
    if (t == 1023) blocksum[b] = s[1023];
    if (b == 0 && t == 0) rowptr[0] = 0;
}

__global__ __launch_bounds__(64)
void scan2_kernel(int* __restrict__ blocksum, int nb)   // nb <= 64
{
    int t = (int)threadIdx.x;
    int v = (t < nb) ? blocksum[t] : 0;
    #pragma unroll
    for (int off = 1; off < 64; off <<= 1) {
        int a = __shfl_up(v, off, 64);
        if (t >= off) v += a;
    }
    if (t < nb) blocksum[t] = v;
}

__global__ __launch_bounds__(256)
void scan3_kernel(const int* __restrict__ blocksum, int* __restrict__ rowptr,
                  int* __restrict__ cursor, int n)
{
    int j = blockIdx.x * 256 + threadIdx.x;   // 0..n
    if (j > n) return;
    int v;
    if (j == 0) v = 0;
    else {
        int b = (j - 1) >> 10;
        v = rowptr[j] + (b >= 1 ? blocksum[b - 1] : 0);
    }
    rowptr[j] = v;
    if (j < n) cursor[j] = v;
}

__global__ __launch_bounds__(256)
void fill_kernel(const int* __restrict__ srcI, const int* __restrict__ dstI,
                 int* __restrict__ cursor, int* __restrict__ csr_src, int nE)
{
    int e = blockIdx.x * 256 + threadIdx.x;
    if (e < nE) {
        int d = dstI[e];
        int s = srcI[e];
        if ((unsigned)d < (unsigned)N_NODES && (unsigned)s < (unsigned)N_NODES) {
            int pos = atomicAdd(&cursor[d], 1);
            csr_src[pos] = s;
        }
    }
}

// ---------------- CSR aggregation, wave-per-node, 8-deep load pipeline ----------
template<int VPT> struct VecT;
template<> struct VecT<2> { using T = us2; };
template<> struct VecT<4> { using T = us4; };
template<> struct VecT<8> { using T = us8; };

template<int VPT>
__global__ __launch_bounds__(256)
void csr_agg_wave_kernel(const ushort_t* __restrict__ feat,
                         const int* __restrict__ rowptr,
                         const int* __restrict__ csr_src,
                         ushort_t* __restrict__ out, int Ds)
{
    using T = typename VecT<VPT>::T;
    const int wv   = (int)threadIdx.x >> 6;
    const int node = (int)blockIdx.x * 4 + wv;
    if (node >= N_NODES) return;
    const int lane = (int)threadIdx.x & 63;
    const int off0 = lane * VPT;
    const bool act = off0 < Ds;                    // Ds=96: lanes 48..63 idle
    const int off  = act ? off0 : (Ds - VPT);

    const int e0 = rowptr[node], e1 = rowptr[node + 1];
    float acc[VPT];
    #pragma unroll
    for (int i = 0; i < VPT; ++i) acc[i] = 0.0f;

    int e = e0;
    for (; e + 8 <= e1; e += 8) {
        T r[8];
        #pragma unroll
        for (int u = 0; u < 8; ++u) {
            int s = csr_src[e + u];
            r[u] = *(const T*)(feat + (size_t)s * Ds + off);
        }
        #pragma unroll
        for (int u = 0; u < 8; ++u)
            #pragma unroll
            for (int i = 0; i < VPT; ++i) acc[i] += bf2f(r[u][i]);
    }
    for (; e + 4 <= e1; e += 4) {
        T r[4];
        #pragma unroll
        for (int u = 0; u < 4; ++u) {
            int s = csr_src[e + u];
            r[u] = *(const T*)(feat + (size_t)s * Ds + off);
        }
        #pragma unroll
        for (int u = 0; u < 4; ++u)
            #pragma unroll
            for (int i = 0; i < VPT; ++i) acc[i] += bf2f(r[u][i]);
    }
    for (; e < e1; ++e) {
        int s = csr_src[e];
        T r = *(const T*)(feat + (size_t)s * Ds + off);
        #pragma unroll
        for (int i = 0; i < VPT; ++i) acc[i] += bf2f(r[i]);
    }

    if (act) {
        T o;
        #pragma unroll
        for (int i = 0; i < VPT; ++i) o[i] = f2bf(acc[i]);
        *(T*)(out + (size_t)node * Ds + off0) = o;
    }
}

// ---------------- bf16 MFMA GEMM, register-pipelined K-loop (r5, verified) ------
// out = act( A1@W1t^T + A2@W2t^T + bias ),  A*: bf16 [M][K], W*t: bf16 [Fo][K]
// Tile: 128 rows x (NT*32) cols, BK=32. 4 waves 2x2; wave = 64 x NT*16.
template<int NT>
__global__ __launch_bounds__(256, 2)
void mfma_gemm_kernel(const ushort_t* __restrict__ A1,
                      const ushort_t* __restrict__ A2,
                      const ushort_t* __restrict__ W1t,
                      const ushort_t* __restrict__ W2t,
                      const float* __restrict__ bias,
                      void* __restrict__ outp,
                      int M, int K, int Fo, int relu, int out_bf16)
{
    constexpr int BN    = NT * 32;     // tile width
    constexpr int NBT   = NT * 2;      // B n-tiles of 16
    constexpr int BT_PW = NBT / 4;     // B-tiles staged per wave
    __shared__ __align__(16) ushort_t Al[8 * 512];   // 8 m-tiles, lane-ordered
    __shared__ __align__(16) ushort_t Bl[NBT * 512];
    const int tid = (int)threadIdx.x;
    const int l   = tid & 63;
    const int w   = tid >> 6;
    const int q   = l >> 4;
    const int r15 = l & 15;
    const int bm  = blockIdx.y * 128;
    const int bn  = blockIdx.x * BN;
    const int wm  = w >> 1, wn = w & 1;

    const int s1 = K >> 5;                       // steps per pass
    const int nsteps = A2 ? (2 * s1) : s1;

    v4f acc[4][NT];
    #pragma unroll
    for (int mt = 0; mt < 4; ++mt)
        #pragma unroll
        for (int nt = 0; nt < NT; ++nt)
            acc[mt][nt] = (v4f){0.0f, 0.0f, 0.0f, 0.0f};

    u4 ra[2], rb[BT_PW];
    auto load_step = [&](int step) {
        const ushort_t* A  = (step >= s1) ? A2  : A1;
        const ushort_t* Bt = (step >= s1) ? W2t : W1t;
        const int k0 = ((step >= s1) ? (step - s1) : step) << 5;
        #pragma unroll
        for (int ii = 0; ii < 2; ++ii) {
            int it  = w * 2 + ii;
            int row = bm + it * 16 + r15;
            if (row < M) ra[ii] = *(const u4*)(A + (size_t)row * K + k0 + q * 8);
            else         ra[ii] = (u4){0u, 0u, 0u, 0u};
        }
        #pragma unroll
        for (int jj = 0; jj < BT_PW; ++jj) {
            int jt  = w * BT_PW + jj;
            int col = bn + jt * 16 + r15;          // Fo multiple of BN
            rb[jj] = *(const u4*)(Bt + (size_t)col * K + k0 + q * 8);
        }
    };

    load_step(0);
    for (int step = 0; step < nsteps; ++step) {
        __syncthreads();   // prior frag reads done before LDS overwrite
        #pragma unroll
        for (int ii = 0; ii < 2; ++ii)
            *(u4*)(Al + (size_t)(w * 2 + ii) * 512 + l * 8) = ra[ii];
        #pragma unroll
        for (int jj = 0; jj < BT_PW; ++jj)
            *(u4*)(Bl + (size_t)(w * BT_PW + jj) * 512 + l * 8) = rb[jj];
        if (step + 1 < nsteps) load_step(step + 1);   // in flight across MFMAs
        __syncthreads();   // LDS writes visible
        v8s af[4], bf[NT];
        #pragma unroll
        for (int mt = 0; mt < 4; ++mt)
            af[mt] = *(const v8s*)(Al + (size_t)(wm * 4 + mt) * 512 + l * 8);
        #pragma unroll
        for (int nt = 0; nt < NT; ++nt)
            bf[nt] = *(const v8s*)(Bl + (size_t)(wn * NT + nt) * 512 + l * 8);
        #pragma unroll
        for (int mt = 0; mt < 4; ++mt)
            #pragma unroll
            for (int nt = 0; nt < NT; ++nt)
                acc[mt][nt] = __builtin_amdgcn_mfma_f32_16x16x32_bf16(
                    af[mt], bf[nt], acc[mt][nt], 0, 0, 0);
    }

    // epilogue: C/D map col=lane&15, row=q*4+reg
    #pragma unroll
    for (int nt = 0; nt < NT; ++nt) {
        int col = bn + wn * (NT * 16) + nt * 16 + r15;
        float bb = bias[col];
        #pragma unroll
        for (int mt = 0; mt < 4; ++mt) {
            #pragma unroll
            for (int p = 0; p < 4; ++p) {
                int row = bm + wm * 64 + mt * 16 + q * 4 + p;
                if (row < M) {
                    float v = acc[mt][nt][p] + bb;
                    if (relu) v = fmaxf(v, 0.0f);
                    if (out_bf16) ((ushort_t*)outp)[(size_t)row * Fo + col] = f2bf(v);
                    else          ((float*)outp)[(size_t)row * Fo + col]   = v;
                }
            }
        }
    }
}

// ---------------- LayerNorm(128) + ReLU + x_atom + atomic pool -----------------
__global__ __launch_bounds__(128)
void ln_relu_pool_kernel(const float* __restrict__ z,
                         const float* __restrict__ gamma,
                         const float* __restrict__ beta,
                         const int* __restrict__ batch,
                         float* __restrict__ x_atom,
                         float* __restrict__ pooled)
{
    int row = (int)blockIdx.x;
    int t = (int)threadIdx.x;     // 0..127
    float v = z[(long long)row * 128 + t];

    __shared__ float red[2];
    float s = v;
    #pragma unroll
    for (int o = 32; o >= 1; o >>= 1) s += __shfl_xor(s, o, 64);
    int wave = t >> 6;
    if ((t & 63) == 0) red[wave] = s;
    __syncthreads();
    float mean = (red[0] + red[1]) * (1.0f / 128.0f);

    float d = v - mean;
    float s2 = d * d;
    #pragma unroll
    for (int o = 32; o >= 1; o >>= 1) s2 += __shfl_xor(s2, o, 64);
    __syncthreads();
    if ((t & 63) == 0) red[wave] = s2;
    __syncthreads();
    float var = (red[0] + red[1]) * (1.0f / 128.0f);

    float y = d * rsqrtf(var + 1e-5f) * gamma[t] + beta[t];
    y = fmaxf(y, 0.0f);
    x_atom[(long long)row * 128 + t] = y;
    int b = batch[row];
    if ((unsigned)b < (unsigned)N_GRAPHS)
        atomicAdd(pooled + (long long)b * 128 + t, y);
}

extern "C" void kernel_launch(void* const* d_in, const int* in_sizes, int n_in,
                              void* d_out, int out_size, void* d_ws, size_t ws_size,
                              hipStream_t stream)
{
    const float* x     = (const float*)d_in[0];
    const int*   ei    = (const int*)d_in[1];
    const int*   batch = (const int*)d_in[2];
    const float* W1r   = (const float*)d_in[3];
    const float* b1    = (const float*)d_in[4];
    const float* W1o   = (const float*)d_in[5];
    const float* W2r   = (const float*)d_in[6];
    const float* b2    = (const float*)d_in[7];
    const float* W2o   = (const float*)d_in[8];
    const float* W3r   = (const float*)d_in[9];
    const float* b3    = (const float*)d_in[10];
    const float* W3o   = (const float*)d_in[11];
    const float* Wfc   = (const float*)d_in[12];
    const float* bfc   = (const float*)d_in[13];
    const float* lng   = (const float*)d_in[14];
    const float* lnb   = (const float*)d_in[15];

    const size_t WS_NEED = 204800000;
    if (ws_size < WS_NEED) {
        hipMemsetAsync(d_out, 0, (size_t)out_size * sizeof(float), stream);
        return;
    }

    char* ws = (char*)d_ws;
    ushort_t* xb   = (ushort_t*)(ws + 0);            // 50000x96 bf16
    ushort_t* h1   = (ushort_t*)(ws + 9600000);      // 50000x256 bf16
    float*    z    = (float*)   (ws + 0);            // 50000x128 f32 (xb/h1 dead)
    ushort_t* aggr = (ushort_t*)(ws + 35200000);     // up to 50000x512 bf16
    ushort_t* h2   = (ushort_t*)(ws + 86400000);     // 50000x512 bf16
    ushort_t* h3   = (ushort_t*)(ws + 137600000);    // 50000x512 bf16
    int* deg    = (int*)(ws + 188800000);            // 50000
    int* rowptr = (int*)(ws + 189000000);            // 50001
    int* cursor = (int*)(ws + 189200128);            // 50000
    int* csrsrc = (int*)(ws + 189400128);            // 800000
    int* blksum = (int*)(ws + 192600128);            // 64
    ushort_t* wt = (ushort_t*)(ws + 192600512);
    ushort_t* w1r_t = wt;                 // 256x96   @0
    ushort_t* w1o_t = wt + 24576;         // 256x96
    ushort_t* w2r_t = wt + 49152;         // 512x256
    ushort_t* w2o_t = wt + 180224;        // 512x256
    ushort_t* w3r_t = wt + 311296;        // 512x512
    ushort_t* w3o_t = wt + 573440;        // 512x512
    ushort_t* wfc_t = wt + 835584;        // 128x512

    float* x_atom = (float*)d_out;
    float* pooled = x_atom + (size_t)N_NODES * OUT_DIM;

    const int* src = ei;
    const int* dst = ei + N_EDGES;

    // ---- conversions: all weights in ONE launch; x pad+cast ----
    wt_all_kernel<<<(901120 + 255) / 256, 256, 0, stream>>>(W1r, W1o, W2r, W2o,
                                                            W3r, W3o, Wfc, wt);
    pad_cast_kernel<<<((N_NODES * K1P) + 255) / 256, 256, 0, stream>>>(x, xb, N_NODES, IN_DIM, K1P);

    // ---- CSR build ----
    hipMemsetAsync(deg, 0, N_NODES * sizeof(int), stream);
    hist_kernel<<<(N_EDGES + 255) / 256, 256, 0, stream>>>(dst, deg, N_EDGES);
    {
        int nb = (N_NODES + 1023) / 1024;   // 49
        scan1_kernel<<<nb, 1024, 0, stream>>>(deg, rowptr, blksum, N_NODES);
        scan2_kernel<<<1, 64, 0, stream>>>(blksum, nb);
        scan3_kernel<<<(N_NODES + 1 + 255) / 256, 256, 0, stream>>>(blksum, rowptr, cursor, N_NODES);
    }
    fill_kernel<<<(N_EDGES + 255) / 256, 256, 0, stream>>>(src, dst, cursor, csrsrc, N_EDGES);

    const int GY = (N_NODES + 127) / 128;
    const int AGG_BLKS = (N_NODES + 3) / 4;

    // ---- layer 1: 78(pad96) -> 256 ----
    csr_agg_wave_kernel<2><<<AGG_BLKS, 256, 0, stream>>>(xb, rowptr, csrsrc, aggr, K1P);
    {
        dim3 g(HID / 256, GY);
        mfma_gemm_kernel<8><<<g, 256, 0, stream>>>(aggr, xb, w1r_t, w1o_t, b1, h1,
                                                   N_NODES, K1P, HID, 1, 1);
    }
    // ---- layer 2: 256 -> 512 ----
    csr_agg_wave_kernel<4><<<AGG_BLKS, 256, 0, stream>>>(h1, rowptr, csrsrc, aggr, HID);
    {
        dim3 g((2 * HID) / 256, GY);
        mfma_gemm_kernel<8><<<g, 256, 0, stream>>>(aggr, h1, w2r_t, w2o_t, b2, h2,
                                                   N_NODES, HID, 2 * HID, 1, 1);
    }
    // ---- layer 3: 512 -> 512 ----
    csr_agg_wave_kernel<8><<<AGG_BLKS, 256, 0, stream>>>(h2, rowptr, csrsrc, aggr, 2 * HID);
    {
        dim3 g((2 * HID) / 256, GY);
        mfma_gemm_kernel<8><<<g, 256, 0, stream>>>(aggr, h2, w3r_t, w3o_t, b3, h3,
                                                   N_NODES, 2 * HID, 2 * HID, 1, 1);
    }
    // ---- fc: 512 -> 128, fp32 out, no relu ----
    {
        dim3 g(OUT_DIM / 128, GY);
        mfma_gemm_kernel<4><<<g, 256, 0, stream>>>(h3, nullptr, wfc_t, nullptr, bfc, z,
                                                   N_NODES, 2 * HID, OUT_DIM, 0, 0);
    }
    // ---- LN + ReLU + pool ----
    hipMemsetAsync(pooled, 0, (size_t)N_GRAPHS * OUT_DIM * sizeof(float), stream);
    ln_relu_pool_kernel<<<N_NODES, 128, 0, stream>>>(z, lng, lnb, batch, x_atom, pooled);
}